// Round 1
// baseline (8463.936 us; speedup 1.0000x reference)
//
#include <hip/hip_runtime.h>
#include <math.h>

#define NN 100000
#define HH 128
#define NCLS 10
#define NGRAPH 256
#define EPSLN 1e-5f

// ---------------- CSR build ----------------
__global__ void count_deg(const int* __restrict__ dst, int* __restrict__ deg, int E){
  int e = blockIdx.x*256 + threadIdx.x;
  if (e < E) atomicAdd(&deg[dst[e]], 1);
}

__global__ void block_sum(const int* __restrict__ deg, int* __restrict__ bsum, int n){
  __shared__ int sm[1024];
  int tid = threadIdx.x;
  int i = blockIdx.x*1024 + tid;
  sm[tid] = (i < n) ? deg[i] : 0;
  __syncthreads();
  for (int s = 512; s > 0; s >>= 1){
    if (tid < s) sm[tid] += sm[tid+s];
    __syncthreads();
  }
  if (tid == 0) bsum[blockIdx.x] = sm[0];
}

__global__ void scan_mid(int* bsum, int nb, int* row_ptr, int n,
                         float* stats, float* params){
  if (threadIdx.x == 0 && blockIdx.x == 0){
    int run = 0;
    for (int b = 0; b < nb; b++){ int t = bsum[b]; bsum[b] = run; run += t; }
    row_ptr[n] = run;
    for (int i = 0; i < 6; i++) stats[i] = 0.f;
    params[0] = 0.f;  // mu for layer-0 conv input (no LN yet)
    params[1] = 1.f;  // rsig
  }
}

__global__ void scan_final(const int* __restrict__ deg, const int* __restrict__ boff,
                           int* __restrict__ row_ptr, int* __restrict__ cursor,
                           float* __restrict__ dinv, int n){
  __shared__ int sm[1024];
  int tid = threadIdx.x;
  int i = blockIdx.x*1024 + tid;
  int v = (i < n) ? deg[i] : 0;
  sm[tid] = v;
  __syncthreads();
  for (int s = 1; s < 1024; s <<= 1){
    int t = (tid >= s) ? sm[tid-s] : 0;
    __syncthreads();
    sm[tid] += t;
    __syncthreads();
  }
  if (i < n){
    int rp = boff[blockIdx.x] + sm[tid] - v;   // exclusive
    row_ptr[i] = rp;
    cursor[i] = rp;
    dinv[i] = rsqrtf((float)(v + 1));          // +1 self-loop; deg>=1 always
  }
}

__global__ void fill_csr(const int* __restrict__ src, const int* __restrict__ dst,
                         int* __restrict__ cursor, int* __restrict__ csr, int E){
  int e = blockIdx.x*256 + threadIdx.x;
  if (e < E){
    int p = atomicAdd(&cursor[dst[e]], 1);
    csr[p] = src[e];
  }
}

__global__ void colsum_kernel(const float* __restrict__ W, float* __restrict__ cs){
  const float* w = W + blockIdx.x*HH*HH;
  float s = 0.f;
  for (int k = 0; k < HH; k++) s += w[k*HH + threadIdx.x];
  cs[blockIdx.x*HH + threadIdx.x] = s;
}

// ---------------- GEMM: out = epilogue(A @ W) ----------------
// mode 0 (lin1):  out = relu(A@W + bias)
// mode 1 (conv):  out = dinv[row] * rsig * ((A@W) - mu*colsum(W))   [LN folded]
__global__ __launch_bounds__(256) void gemm128(
    const float* __restrict__ A, const float* __restrict__ W,
    const float* __restrict__ bias,
    const float* __restrict__ dinv,
    const float* __restrict__ params,   // {mu, rsig}
    const float* __restrict__ colsum,
    float* __restrict__ out, int n, int mode)
{
  __shared__ float Wl[128*64];   // [k][c] stride 64
  __shared__ float Hl[64*128];   // [r][k] stride 128, XOR-swizzled words
  int tid = threadIdx.x;
  int rb = blockIdx.x*64, cb = blockIdx.y*64;

  #pragma unroll
  for (int rep = 0; rep < 8; rep++){
    int idx = rep*256 + tid;
    int k = idx >> 4, c4 = idx & 15;
    float4 v = *(const float4*)&W[k*HH + cb + c4*4];
    *(float4*)&Wl[k*64 + c4*4] = v;
  }
  #pragma unroll
  for (int rep = 0; rep < 8; rep++){
    int idx = rep*256 + tid;
    int r = idx >> 5, k4 = idx & 31;
    int row = rb + r;
    float4 v = make_float4(0.f,0.f,0.f,0.f);
    if (row < n) v = *(const float4*)&A[(size_t)row*HH + k4*4];
    int sw = ((r >> 2) & 7) << 2;
    *(float4*)&Hl[r*128 + ((k4*4) ^ sw)] = v;
  }
  __syncthreads();

  int tx = tid & 15, ty = tid >> 4;
  float4 acc0 = make_float4(0,0,0,0), acc1 = acc0, acc2 = acc0, acc3 = acc0;
  int sw = (ty & 7) << 2;
  #pragma unroll 4
  for (int k4 = 0; k4 < 32; k4++){
    int hoff = (k4*4) ^ sw;
    float4 h0 = *(float4*)&Hl[(ty*4+0)*128 + hoff];
    float4 h1 = *(float4*)&Hl[(ty*4+1)*128 + hoff];
    float4 h2 = *(float4*)&Hl[(ty*4+2)*128 + hoff];
    float4 h3 = *(float4*)&Hl[(ty*4+3)*128 + hoff];
    float4 w0 = *(float4*)&Wl[(k4*4+0)*64 + tx*4];
    float4 w1 = *(float4*)&Wl[(k4*4+1)*64 + tx*4];
    float4 w2 = *(float4*)&Wl[(k4*4+2)*64 + tx*4];
    float4 w3 = *(float4*)&Wl[(k4*4+3)*64 + tx*4];
    #define FMA4(ACC,HV) \
      ACC.x = fmaf(HV.x, w0.x, ACC.x); ACC.y = fmaf(HV.x, w0.y, ACC.y); \
      ACC.z = fmaf(HV.x, w0.z, ACC.z); ACC.w = fmaf(HV.x, w0.w, ACC.w); \
      ACC.x = fmaf(HV.y, w1.x, ACC.x); ACC.y = fmaf(HV.y, w1.y, ACC.y); \
      ACC.z = fmaf(HV.y, w1.z, ACC.z); ACC.w = fmaf(HV.y, w1.w, ACC.w); \
      ACC.x = fmaf(HV.z, w2.x, ACC.x); ACC.y = fmaf(HV.z, w2.y, ACC.y); \
      ACC.z = fmaf(HV.z, w2.z, ACC.z); ACC.w = fmaf(HV.z, w2.w, ACC.w); \
      ACC.x = fmaf(HV.w, w3.x, ACC.x); ACC.y = fmaf(HV.w, w3.y, ACC.y); \
      ACC.z = fmaf(HV.w, w3.z, ACC.z); ACC.w = fmaf(HV.w, w3.w, ACC.w);
    FMA4(acc0, h0) FMA4(acc1, h1) FMA4(acc2, h2) FMA4(acc3, h3)
    #undef FMA4
  }

  float mu = 0.f, rsig = 1.f;
  if (mode == 1){ mu = params[0]; rsig = params[1]; }
  int col = cb + tx*4;
  float4 cs4 = make_float4(0,0,0,0), b4 = make_float4(0,0,0,0);
  if (mode == 1) cs4 = *(const float4*)&colsum[col];
  else           b4  = *(const float4*)&bias[col];

  float4 accs[4] = {acc0, acc1, acc2, acc3};
  #pragma unroll
  for (int j = 0; j < 4; j++){
    int row = rb + ty*4 + j;
    if (row < n){
      float4 a = accs[j];
      if (mode == 0){
        a.x = fmaxf(a.x + b4.x, 0.f); a.y = fmaxf(a.y + b4.y, 0.f);
        a.z = fmaxf(a.z + b4.z, 0.f); a.w = fmaxf(a.w + b4.w, 0.f);
      } else {
        float d = dinv[row] * rsig;
        a.x = d*(a.x - mu*cs4.x); a.y = d*(a.y - mu*cs4.y);
        a.z = d*(a.z - mu*cs4.z); a.w = d*(a.w - mu*cs4.w);
      }
      *(float4*)&out[(size_t)row*HH + col] = a;
    }
  }
}

// ---------------- Aggregation (pull over CSR) ----------------
// h[d] = relu(dinv[d]*(hw2[d] + sum_{s in in(d)} hw2[s]) + b); fused LN stats
__global__ __launch_bounds__(256) void aggregate(
    const float* __restrict__ hw, const int* __restrict__ row_ptr,
    const int* __restrict__ csr, const float* __restrict__ dinv,
    const float* __restrict__ bias, float* __restrict__ hout,
    float* __restrict__ stats)
{
  int wave = threadIdx.x >> 6, lane = threadIdx.x & 63;
  int node = blockIdx.x*4 + wave;
  const float2* hw2 = (const float2*)hw;
  float2 acc = hw2[(size_t)node*64 + lane];   // self loop (dinv[d]^2 * raw)
  int s0 = row_ptr[node], s1 = row_ptr[node+1];
  int j = s0;
  for (; j + 4 <= s1; j += 4){
    int a = csr[j], b = csr[j+1], c = csr[j+2], d = csr[j+3];
    float2 va = hw2[(size_t)a*64 + lane];
    float2 vb = hw2[(size_t)b*64 + lane];
    float2 vc = hw2[(size_t)c*64 + lane];
    float2 vd = hw2[(size_t)d*64 + lane];
    acc.x += (va.x + vb.x) + (vc.x + vd.x);
    acc.y += (va.y + vb.y) + (vc.y + vd.y);
  }
  for (; j < s1; j++){
    int a = csr[j];
    float2 v = hw2[(size_t)a*64 + lane];
    acc.x += v.x; acc.y += v.y;
  }
  float dv = dinv[node];
  float rx = fmaxf(fmaf(dv, acc.x, bias[lane*2+0]), 0.f);
  float ry = fmaxf(fmaf(dv, acc.y, bias[lane*2+1]), 0.f);
  float2 res; res.x = rx; res.y = ry;
  ((float2*)hout)[(size_t)node*64 + lane] = res;

  float s = rx + ry;
  float q = rx*rx + ry*ry;
  for (int off = 32; off > 0; off >>= 1){
    s += __shfl_xor(s, off, 64);
    q += __shfl_xor(q, off, 64);
  }
  if (lane == 0){
    atomicAdd(&stats[0], s);
    atomicAdd(&stats[1], q);
  }
}

__global__ void finalize_ln(const float* __restrict__ stats, float* __restrict__ params){
  if (threadIdx.x == 0){
    const float inv = 1.f / ((float)NN * (float)HH);
    float mu = stats[0] * inv;
    float var = stats[1] * inv - mu*mu;
    params[0] = mu;
    params[1] = rsqrtf(var + EPSLN);
  }
}

// ---------------- Pool + MLP + log_softmax ----------------
__global__ __launch_bounds__(128) void pool_mlp(
    const float* __restrict__ h, const int* __restrict__ batch,
    const float* __restrict__ params, const float* __restrict__ W1,
    const float* __restrict__ b1, const float* __restrict__ W2,
    const float* __restrict__ b2, float* __restrict__ out, int n)
{
  __shared__ float pooled[128];
  __shared__ float gact[128];
  __shared__ float sc[16];
  __shared__ int se[2];
  int g = blockIdx.x, tid = threadIdx.x;
  if (tid < 2){
    int v = g + tid;
    int lo = 0, hi = n;
    while (lo < hi){ int mid = (lo+hi) >> 1; if (batch[mid] < v) lo = mid+1; else hi = mid; }
    se[tid] = lo;
  }
  __syncthreads();
  int start = se[0], end = se[1];
  float sum = 0.f;
  for (int v = start; v < end; v++) sum += h[(size_t)v*HH + tid];
  float cnt = (float)((end - start) > 0 ? (end - start) : 1);
  float mu = params[0], rs = params[1];
  pooled[tid] = rs * (sum / cnt - mu);
  __syncthreads();
  float a = b1[tid];
  for (int k = 0; k < HH; k++) a = fmaf(pooled[k], W1[k*HH + tid], a);
  gact[tid] = fmaxf(a, 0.f);
  __syncthreads();
  if (tid < NCLS){
    float s = b2[tid];
    for (int k = 0; k < HH; k++) s = fmaf(gact[k], W2[k*NCLS + tid], s);
    sc[tid] = s;
  }
  __syncthreads();
  if (tid == 0){
    float m = sc[0];
    for (int j = 1; j < NCLS; j++) m = fmaxf(m, sc[j]);
    float lse = 0.f;
    for (int j = 0; j < NCLS; j++) lse += expf(sc[j] - m);
    lse = logf(lse);
    for (int j = 0; j < NCLS; j++) out[g*NCLS + j] = sc[j] - m - lse;
  }
}

// ---------------- launch ----------------
extern "C" void kernel_launch(void* const* d_in, const int* in_sizes, int n_in,
                              void* d_out, int out_size, void* d_ws, size_t ws_size,
                              hipStream_t stream)
{
  const float* x      = (const float*)d_in[0];
  const int*   ei     = (const int*)d_in[1];
  const int*   batch  = (const int*)d_in[2];
  const float* lin1_W = (const float*)d_in[3];
  const float* lin1_b = (const float*)d_in[4];
  const float* conv_W = (const float*)d_in[5];
  const float* conv_b = (const float*)d_in[6];
  const float* mlp_W1 = (const float*)d_in[7];
  const float* mlp_b1 = (const float*)d_in[8];
  const float* mlp_W2 = (const float*)d_in[9];
  const float* mlp_b2 = (const float*)d_in[10];

  const int N = in_sizes[2];      // 100000
  const int E = in_sizes[1] / 2;  // 3200000

  char* ws = (char*)d_ws;
  size_t off = 0;
  auto alloc = [&](size_t bytes)->char*{
    char* p = ws + off; off += (bytes + 255) & ~(size_t)255; return p;
  };
  float* bufA    = (float*)alloc((size_t)N*HH*4);
  float* bufB    = (float*)alloc((size_t)N*HH*4);
  int*   csr     = (int*)  alloc((size_t)E*4);
  int*   row_ptr = (int*)  alloc((size_t)(N+1)*4);
  int*   cursor  = (int*)  alloc((size_t)N*4);
  int*   deg     = (int*)  alloc((size_t)N*4);
  float* dinv    = (float*)alloc((size_t)N*4);
  int*   bsum    = (int*)  alloc(4096);
  float* stats   = (float*)alloc(256);
  float* params  = (float*)alloc(256);
  float* csums   = (float*)alloc(3*HH*4);

  const int* srcp = ei;
  const int* dstp = ei + E;

  hipMemsetAsync(deg, 0, (size_t)N*4, stream);
  count_deg<<<(E+255)/256, 256, 0, stream>>>(dstp, deg, E);
  int nb = (N + 1023) / 1024;
  block_sum<<<nb, 1024, 0, stream>>>(deg, bsum, N);
  scan_mid<<<1, 64, 0, stream>>>(bsum, nb, row_ptr, N, stats, params);
  scan_final<<<nb, 1024, 0, stream>>>(deg, bsum, row_ptr, cursor, dinv, N);
  fill_csr<<<(E+255)/256, 256, 0, stream>>>(srcp, dstp, cursor, csr, E);
  colsum_kernel<<<3, 128, 0, stream>>>(conv_W, csums);

  dim3 ggrid((N+63)/64, 2);
  gemm128<<<ggrid, 256, 0, stream>>>(x, lin1_W, lin1_b, nullptr, nullptr, nullptr,
                                     bufA, N, 0);
  for (int i = 0; i < 3; i++){
    gemm128<<<ggrid, 256, 0, stream>>>(bufA, conv_W + (size_t)i*HH*HH, nullptr,
                                       dinv, params + 2*i, csums + i*HH,
                                       bufB, N, 1);
    aggregate<<<N/4, 256, 0, stream>>>(bufB, row_ptr, csr, dinv,
                                       conv_b + i*HH, bufA, stats + 2*i);
    finalize_ln<<<1, 64, 0, stream>>>(stats + 2*i, params + 2*(i+1));
  }
  pool_mlp<<<NGRAPH, 128, 0, stream>>>(bufA, batch, params + 6,
                                       mlp_W1, mlp_b1, mlp_W2, mlp_b2,
                                       (float*)d_out, N);
}

// Round 2
// 1539.121 us; speedup vs baseline: 5.4992x; 5.4992x over previous
//
#include <hip/hip_runtime.h>
#include <math.h>

#define NN 100000
#define HH 128
#define NCLS 10
#define NGRAPH 256
#define EPSLN 1e-5f

// ---------------- CSR build ----------------
__global__ void count_deg(const int* __restrict__ dst, int* __restrict__ deg, int E){
  int e = blockIdx.x*256 + threadIdx.x;
  if (e < E) atomicAdd(&deg[dst[e]], 1);
}

__global__ void block_sum(const int* __restrict__ deg, int* __restrict__ bsum, int n){
  __shared__ int sm[1024];
  int tid = threadIdx.x;
  int i = blockIdx.x*1024 + tid;
  sm[tid] = (i < n) ? deg[i] : 0;
  __syncthreads();
  for (int s = 512; s > 0; s >>= 1){
    if (tid < s) sm[tid] += sm[tid+s];
    __syncthreads();
  }
  if (tid == 0) bsum[blockIdx.x] = sm[0];
}

__global__ void scan_mid(int* bsum, int nb, int* row_ptr, int n, float* params){
  if (threadIdx.x == 0 && blockIdx.x == 0){
    int run = 0;
    for (int b = 0; b < nb; b++){ int t = bsum[b]; bsum[b] = run; run += t; }
    row_ptr[n] = run;
    params[0] = 0.f;  // mu for layer-0 conv input (no LN yet)
    params[1] = 1.f;  // rsig
  }
}

__global__ void scan_final(const int* __restrict__ deg, const int* __restrict__ boff,
                           int* __restrict__ row_ptr, int* __restrict__ cursor,
                           float* __restrict__ dinv, int n){
  __shared__ int sm[1024];
  int tid = threadIdx.x;
  int i = blockIdx.x*1024 + tid;
  int v = (i < n) ? deg[i] : 0;
  sm[tid] = v;
  __syncthreads();
  for (int s = 1; s < 1024; s <<= 1){
    int t = (tid >= s) ? sm[tid-s] : 0;
    __syncthreads();
    sm[tid] += t;
    __syncthreads();
  }
  if (i < n){
    int rp = boff[blockIdx.x] + sm[tid] - v;   // exclusive
    row_ptr[i] = rp;
    cursor[i] = rp;
    dinv[i] = rsqrtf((float)(v + 1));          // +1 self-loop
  }
}

__global__ void fill_csr(const int* __restrict__ src, const int* __restrict__ dst,
                         int* __restrict__ cursor, int* __restrict__ csr, int E){
  int e = blockIdx.x*256 + threadIdx.x;
  if (e < E){
    int p = atomicAdd(&cursor[dst[e]], 1);
    csr[p] = src[e];
  }
}

__global__ void colsum_kernel(const float* __restrict__ W, float* __restrict__ cs){
  const float* w = W + blockIdx.x*HH*HH;
  float s = 0.f;
  for (int k = 0; k < HH; k++) s += w[k*HH + threadIdx.x];
  cs[blockIdx.x*HH + threadIdx.x] = s;
}

// ---------------- GEMM: out = epilogue(A @ W) ----------------
// mode 0 (lin1):  out = relu(A@W + bias)
// mode 1 (conv):  out = dinv[row] * rsig * ((A@W) - mu*colsum(W))   [LN folded]
__global__ __launch_bounds__(256) void gemm128(
    const float* __restrict__ A, const float* __restrict__ W,
    const float* __restrict__ bias,
    const float* __restrict__ dinv,
    const float* __restrict__ params,   // {mu, rsig}
    const float* __restrict__ colsum,
    float* __restrict__ out, int n, int mode)
{
  __shared__ float Wl[128*64];   // [k][c] stride 64
  __shared__ float Hl[64*128];   // [r][k] stride 128, XOR-swizzled words
  int tid = threadIdx.x;
  int rb = blockIdx.x*64, cb = blockIdx.y*64;

  #pragma unroll
  for (int rep = 0; rep < 8; rep++){
    int idx = rep*256 + tid;
    int k = idx >> 4, c4 = idx & 15;
    float4 v = *(const float4*)&W[k*HH + cb + c4*4];
    *(float4*)&Wl[k*64 + c4*4] = v;
  }
  #pragma unroll
  for (int rep = 0; rep < 8; rep++){
    int idx = rep*256 + tid;
    int r = idx >> 5, k4 = idx & 31;
    int row = rb + r;
    float4 v = make_float4(0.f,0.f,0.f,0.f);
    if (row < n) v = *(const float4*)&A[(size_t)row*HH + k4*4];
    int sw = ((r >> 2) & 7) << 2;
    *(float4*)&Hl[r*128 + ((k4*4) ^ sw)] = v;
  }
  __syncthreads();

  int tx = tid & 15, ty = tid >> 4;
  float4 acc0 = make_float4(0,0,0,0), acc1 = acc0, acc2 = acc0, acc3 = acc0;
  int sw = (ty & 7) << 2;
  #pragma unroll 4
  for (int k4 = 0; k4 < 32; k4++){
    int hoff = (k4*4) ^ sw;
    float4 h0 = *(float4*)&Hl[(ty*4+0)*128 + hoff];
    float4 h1 = *(float4*)&Hl[(ty*4+1)*128 + hoff];
    float4 h2 = *(float4*)&Hl[(ty*4+2)*128 + hoff];
    float4 h3 = *(float4*)&Hl[(ty*4+3)*128 + hoff];
    float4 w0 = *(float4*)&Wl[(k4*4+0)*64 + tx*4];
    float4 w1 = *(float4*)&Wl[(k4*4+1)*64 + tx*4];
    float4 w2 = *(float4*)&Wl[(k4*4+2)*64 + tx*4];
    float4 w3 = *(float4*)&Wl[(k4*4+3)*64 + tx*4];
    #define FMA4(ACC,HV) \
      ACC.x = fmaf(HV.x, w0.x, ACC.x); ACC.y = fmaf(HV.x, w0.y, ACC.y); \
      ACC.z = fmaf(HV.x, w0.z, ACC.z); ACC.w = fmaf(HV.x, w0.w, ACC.w); \
      ACC.x = fmaf(HV.y, w1.x, ACC.x); ACC.y = fmaf(HV.y, w1.y, ACC.y); \
      ACC.z = fmaf(HV.y, w1.z, ACC.z); ACC.w = fmaf(HV.y, w1.w, ACC.w); \
      ACC.x = fmaf(HV.z, w2.x, ACC.x); ACC.y = fmaf(HV.z, w2.y, ACC.y); \
      ACC.z = fmaf(HV.z, w2.z, ACC.z); ACC.w = fmaf(HV.z, w2.w, ACC.w); \
      ACC.x = fmaf(HV.w, w3.x, ACC.x); ACC.y = fmaf(HV.w, w3.y, ACC.y); \
      ACC.z = fmaf(HV.w, w3.z, ACC.z); ACC.w = fmaf(HV.w, w3.w, ACC.w);
    FMA4(acc0, h0) FMA4(acc1, h1) FMA4(acc2, h2) FMA4(acc3, h3)
    #undef FMA4
  }

  float mu = 0.f, rsig = 1.f;
  if (mode == 1){ mu = params[0]; rsig = params[1]; }
  int col = cb + tx*4;
  float4 cs4 = make_float4(0,0,0,0), b4 = make_float4(0,0,0,0);
  if (mode == 1) cs4 = *(const float4*)&colsum[col];
  else           b4  = *(const float4*)&bias[col];

  float4 accs[4] = {acc0, acc1, acc2, acc3};
  #pragma unroll
  for (int j = 0; j < 4; j++){
    int row = rb + ty*4 + j;
    if (row < n){
      float4 a = accs[j];
      if (mode == 0){
        a.x = fmaxf(a.x + b4.x, 0.f); a.y = fmaxf(a.y + b4.y, 0.f);
        a.z = fmaxf(a.z + b4.z, 0.f); a.w = fmaxf(a.w + b4.w, 0.f);
      } else {
        float d = dinv[row] * rsig;
        a.x = d*(a.x - mu*cs4.x); a.y = d*(a.y - mu*cs4.y);
        a.z = d*(a.z - mu*cs4.z); a.w = d*(a.w - mu*cs4.w);
      }
      *(float4*)&out[(size_t)row*HH + col] = a;
    }
  }
}

// ---------------- Aggregation (pull over CSR, block-per-node) ----------------
// One block = one node, 128 threads = 128 features. node is BLOCK-UNIFORM so
// index/row_ptr loads scalarize (s_load, scalar cache), off the vector path.
// 16 gathers issued back-to-back -> 64 cache lines in flight per wave.
__global__ __launch_bounds__(128) void aggregate(
    const float* __restrict__ hw, const int* __restrict__ row_ptr,
    const int* __restrict__ csr, const float* __restrict__ dinv,
    const float* __restrict__ bias, float* __restrict__ hout,
    float2* __restrict__ partials)
{
  int node = blockIdx.x;
  int t = threadIdx.x;
  float acc = hw[(size_t)node*HH + t];   // self loop
  int s0 = row_ptr[node], s1 = row_ptr[node+1];
  int j = s0;
  for (; j + 16 <= s1; j += 16){
    int idx[16];
    #pragma unroll
    for (int u = 0; u < 16; u++) idx[u] = csr[j+u];
    float v[16];
    #pragma unroll
    for (int u = 0; u < 16; u++) v[u] = hw[(size_t)idx[u]*HH + t];
    #pragma unroll
    for (int u = 0; u < 16; u++) acc += v[u];
  }
  for (; j + 4 <= s1; j += 4){
    int idx[4];
    #pragma unroll
    for (int u = 0; u < 4; u++) idx[u] = csr[j+u];
    float v[4];
    #pragma unroll
    for (int u = 0; u < 4; u++) v[u] = hw[(size_t)idx[u]*HH + t];
    acc += (v[0] + v[1]) + (v[2] + v[3]);
  }
  for (; j < s1; j++) acc += hw[(size_t)csr[j]*HH + t];

  float r = fmaxf(fmaf(dinv[node], acc, bias[t]), 0.f);
  hout[(size_t)node*HH + t] = r;

  // per-block LN partial (sum, sumsq) -> no global atomics
  float s = r, q = r*r;
  for (int off = 32; off > 0; off >>= 1){
    s += __shfl_xor(s, off, 64);
    q += __shfl_xor(q, off, 64);
  }
  __shared__ float sm[4];
  int wave = t >> 6, lane = t & 63;
  if (lane == 0){ sm[wave*2] = s; sm[wave*2+1] = q; }
  __syncthreads();
  if (t == 0) partials[node] = make_float2(sm[0] + sm[2], sm[1] + sm[3]);
}

__global__ __launch_bounds__(1024) void finalize_ln(
    const float2* __restrict__ partials, int n, float* __restrict__ params)
{
  int tid = threadIdx.x;
  float s = 0.f, q = 0.f;
  for (int i = tid; i < n; i += 1024){
    float2 p = partials[i];
    s += p.x; q += p.y;
  }
  for (int off = 32; off > 0; off >>= 1){
    s += __shfl_xor(s, off, 64);
    q += __shfl_xor(q, off, 64);
  }
  __shared__ float ssm[16], qsm[16];
  int wave = tid >> 6, lane = tid & 63;
  if (lane == 0){ ssm[wave] = s; qsm[wave] = q; }
  __syncthreads();
  if (tid == 0){
    float S = 0.f, Q = 0.f;
    for (int w = 0; w < 16; w++){ S += ssm[w]; Q += qsm[w]; }
    const float inv = 1.f / ((float)NN * (float)HH);
    float mu = S * inv;
    float var = Q * inv - mu*mu;
    params[0] = mu;
    params[1] = rsqrtf(var + EPSLN);
  }
}

// ---------------- Pool + MLP + log_softmax ----------------
__global__ __launch_bounds__(128) void pool_mlp(
    const float* __restrict__ h, const int* __restrict__ batch,
    const float* __restrict__ params, const float* __restrict__ W1,
    const float* __restrict__ b1, const float* __restrict__ W2,
    const float* __restrict__ b2, float* __restrict__ out, int n)
{
  __shared__ float pooled[128];
  __shared__ float gact[128];
  __shared__ float sc[16];
  __shared__ int se[2];
  int g = blockIdx.x, tid = threadIdx.x;
  if (tid < 2){
    int v = g + tid;
    int lo = 0, hi = n;
    while (lo < hi){ int mid = (lo+hi) >> 1; if (batch[mid] < v) lo = mid+1; else hi = mid; }
    se[tid] = lo;
  }
  __syncthreads();
  int start = se[0], end = se[1];
  float sum = 0.f;
  for (int v = start; v < end; v++) sum += h[(size_t)v*HH + tid];
  float cnt = (float)((end - start) > 0 ? (end - start) : 1);
  float mu = params[0], rs = params[1];
  pooled[tid] = rs * (sum / cnt - mu);
  __syncthreads();
  float a = b1[tid];
  for (int k = 0; k < HH; k++) a = fmaf(pooled[k], W1[k*HH + tid], a);
  gact[tid] = fmaxf(a, 0.f);
  __syncthreads();
  if (tid < NCLS){
    float s = b2[tid];
    for (int k = 0; k < HH; k++) s = fmaf(gact[k], W2[k*NCLS + tid], s);
    sc[tid] = s;
  }
  __syncthreads();
  if (tid == 0){
    float m = sc[0];
    for (int j = 1; j < NCLS; j++) m = fmaxf(m, sc[j]);
    float lse = 0.f;
    for (int j = 0; j < NCLS; j++) lse += expf(sc[j] - m);
    lse = logf(lse);
    for (int j = 0; j < NCLS; j++) out[g*NCLS + j] = sc[j] - m - lse;
  }
}

// ---------------- launch ----------------
extern "C" void kernel_launch(void* const* d_in, const int* in_sizes, int n_in,
                              void* d_out, int out_size, void* d_ws, size_t ws_size,
                              hipStream_t stream)
{
  const float* x      = (const float*)d_in[0];
  const int*   ei     = (const int*)d_in[1];
  const int*   batch  = (const int*)d_in[2];
  const float* lin1_W = (const float*)d_in[3];
  const float* lin1_b = (const float*)d_in[4];
  const float* conv_W = (const float*)d_in[5];
  const float* conv_b = (const float*)d_in[6];
  const float* mlp_W1 = (const float*)d_in[7];
  const float* mlp_b1 = (const float*)d_in[8];
  const float* mlp_W2 = (const float*)d_in[9];
  const float* mlp_b2 = (const float*)d_in[10];

  const int N = in_sizes[2];      // 100000
  const int E = in_sizes[1] / 2;  // 3200000

  char* ws = (char*)d_ws;
  size_t off = 0;
  auto alloc = [&](size_t bytes)->char*{
    char* p = ws + off; off += (bytes + 255) & ~(size_t)255; return p;
  };
  float*  bufA    = (float*)alloc((size_t)N*HH*4);
  float*  bufB    = (float*)alloc((size_t)N*HH*4);
  int*    csr     = (int*)  alloc((size_t)E*4);
  int*    row_ptr = (int*)  alloc((size_t)(N+1)*4);
  int*    cursor  = (int*)  alloc((size_t)N*4);
  int*    deg     = (int*)  alloc((size_t)N*4);
  float*  dinv    = (float*)alloc((size_t)N*4);
  int*    bsum    = (int*)  alloc(4096);
  float*  params  = (float*)alloc(256);
  float*  csums   = (float*)alloc(3*HH*4);
  float2* partials= (float2*)alloc((size_t)N*8);

  const int* srcp = ei;
  const int* dstp = ei + E;

  hipMemsetAsync(deg, 0, (size_t)N*4, stream);
  count_deg<<<(E+255)/256, 256, 0, stream>>>(dstp, deg, E);
  int nb = (N + 1023) / 1024;
  block_sum<<<nb, 1024, 0, stream>>>(deg, bsum, N);
  scan_mid<<<1, 64, 0, stream>>>(bsum, nb, row_ptr, N, params);
  scan_final<<<nb, 1024, 0, stream>>>(deg, bsum, row_ptr, cursor, dinv, N);
  fill_csr<<<(E+255)/256, 256, 0, stream>>>(srcp, dstp, cursor, csr, E);
  colsum_kernel<<<3, 128, 0, stream>>>(conv_W, csums);

  dim3 ggrid((N+63)/64, 2);
  gemm128<<<ggrid, 256, 0, stream>>>(x, lin1_W, lin1_b, nullptr, nullptr, nullptr,
                                     bufA, N, 0);
  for (int i = 0; i < 3; i++){
    gemm128<<<ggrid, 256, 0, stream>>>(bufA, conv_W + (size_t)i*HH*HH, nullptr,
                                       dinv, params + 2*i, csums + i*HH,
                                       bufB, N, 1);
    aggregate<<<N, 128, 0, stream>>>(bufB, row_ptr, csr, dinv,
                                     conv_b + i*HH, bufA, partials);
    finalize_ln<<<1, 1024, 0, stream>>>(partials, N, params + 2*(i+1));
  }
  pool_mlp<<<NGRAPH, 128, 0, stream>>>(bufA, batch, params + 6,
                                       mlp_W1, mlp_b1, mlp_W2, mlp_b2,
                                       (float*)d_out, N);
}

// Round 3
// 884.038 us; speedup vs baseline: 9.5742x; 1.7410x over previous
//
#include <hip/hip_runtime.h>
#include <math.h>

#define NN 100000
#define HH 128
#define NCLS 10
#define NGRAPH 256
#define EPSLN 1e-5f
#define NB 196          // ceil(100000/512) buckets of 512 nodes
#define NBLK 256        // blocks for hist/scatter passes

static __device__ __forceinline__ unsigned short f2bf(float f){
  unsigned u = __float_as_uint(f);
  u = u + 0x7fffu + ((u >> 16) & 1u);   // round-to-nearest-even
  return (unsigned short)(u >> 16);
}
static __device__ __forceinline__ float bf2f(unsigned short h){
  return __uint_as_float(((unsigned)h) << 16);
}

// ---------------- Bucketed CSR build ----------------
// Pass A: per-block bucket histogram; reserve per-(block,bucket) bases.
__global__ __launch_bounds__(1024) void bucket_hist(
    const int* __restrict__ dst, int E,
    int* __restrict__ gbucket, int* __restrict__ blkbase)
{
  __shared__ int lh[NB];
  int tid = threadIdx.x;
  for (int i = tid; i < NB; i += 1024) lh[i] = 0;
  __syncthreads();
  int per = (E + gridDim.x - 1) / gridDim.x;
  int s = blockIdx.x * per, e = min(E, s + per);
  for (int j = s + tid; j < e; j += 1024)
    atomicAdd(&lh[dst[j] >> 9], 1);
  __syncthreads();
  for (int i = tid; i < NB; i += 1024)
    blkbase[blockIdx.x * NB + i] = atomicAdd(&gbucket[i], lh[i]);
}

__global__ void bucket_scan(const int* __restrict__ gbucket,
                            int* __restrict__ bucket_base, int E,
                            int* __restrict__ row_ptr, int N,
                            float* __restrict__ params)
{
  if (threadIdx.x == 0 && blockIdx.x == 0){
    int run = 0;
    for (int b = 0; b < NB; b++){ bucket_base[b] = run; run += gbucket[b]; }
    bucket_base[NB] = run;
    row_ptr[N] = E;
    params[0] = 0.f;   // mu for layer-0 conv (no LN yet)
    params[1] = 1.f;   // rsig
  }
}

// Pass B: scatter packed (dst,src) into bucket-ordered ebuf (dense windows).
__global__ __launch_bounds__(1024) void bucket_scatter(
    const int* __restrict__ src, const int* __restrict__ dst, int E,
    const int* __restrict__ bucket_base, const int* __restrict__ blkbase,
    unsigned long long* __restrict__ ebuf)
{
  __shared__ int lcur[NB];
  int tid = threadIdx.x;
  for (int i = tid; i < NB; i += 1024)
    lcur[i] = bucket_base[i] + blkbase[blockIdx.x * NB + i];
  __syncthreads();
  int per = (E + gridDim.x - 1) / gridDim.x;
  int s = blockIdx.x * per, e = min(E, s + per);
  for (int j = s + tid; j < e; j += 1024){
    int d = dst[j];
    int p = atomicAdd(&lcur[d >> 9], 1);
    ebuf[p] = (((unsigned long long)(unsigned)d) << 32) | (unsigned)src[j];
  }
}

// Pass C: per bucket (512 nodes): local deg + scan -> row_ptr/dinv/cursor,
// then fill csr within the bucket's contiguous window.
__global__ __launch_bounds__(1024) void bucket_fill(
    const unsigned long long* __restrict__ ebuf,
    const int* __restrict__ bucket_base, int N,
    int* __restrict__ row_ptr, float* __restrict__ dinv,
    int* __restrict__ csr)
{
  __shared__ int ldeg[512];
  __shared__ int lscan[512];
  __shared__ int lcur[512];
  int b = blockIdx.x, tid = threadIdx.x;
  int node0 = b << 9;
  int nn = min(512, N - node0);
  for (int i = tid; i < 512; i += 1024) ldeg[i] = 0;
  __syncthreads();
  int s = bucket_base[b], e = bucket_base[b + 1];
  for (int j = s + tid; j < e; j += 1024){
    int d = (int)(ebuf[j] >> 32);
    atomicAdd(&ldeg[d - node0], 1);
  }
  __syncthreads();
  if (tid < 512) lscan[tid] = ldeg[tid];
  __syncthreads();
  for (int off = 1; off < 512; off <<= 1){
    int v = (tid < 512 && tid >= off) ? lscan[tid - off] : 0;
    __syncthreads();
    if (tid < 512) lscan[tid] += v;
    __syncthreads();
  }
  if (tid < nn){
    int rp = s + lscan[tid] - ldeg[tid];   // exclusive
    row_ptr[node0 + tid] = rp;
    lcur[tid] = rp;
    dinv[node0 + tid] = rsqrtf((float)(ldeg[tid] + 1));  // +1 self-loop
  }
  __syncthreads();
  for (int j = s + tid; j < e; j += 1024){
    unsigned long long pk = ebuf[j];
    int d = (int)(pk >> 32);
    int p = atomicAdd(&lcur[d - node0], 1);
    csr[p] = (int)(unsigned)pk;
  }
}

__global__ void colsum_kernel(const float* __restrict__ W, float* __restrict__ cs){
  const float* w = W + blockIdx.x*HH*HH;
  float s = 0.f;
  for (int k = 0; k < HH; k++) s += w[k*HH + threadIdx.x];
  cs[blockIdx.x*HH + threadIdx.x] = s;
}

// ---------------- GEMM: out = epilogue(A @ W) ----------------
// mode 0 (lin1):  out(f32) = relu(A@W + bias)
// mode 1 (conv):  out(bf16x2 packed) = dinv[row]*rsig*((A@W) - mu*colsum(W))
__global__ __launch_bounds__(256) void gemm128(
    const float* __restrict__ A, const float* __restrict__ W,
    const float* __restrict__ bias,
    const float* __restrict__ dinv,
    const float* __restrict__ params,   // {mu, rsig}
    const float* __restrict__ colsum,
    float* __restrict__ out, int n, int mode)
{
  __shared__ float Wl[128*64];   // [k][c] stride 64
  __shared__ float Hl[64*128];   // [r][k] stride 128, XOR-swizzled words
  int tid = threadIdx.x;
  int rb = blockIdx.x*64, cb = blockIdx.y*64;

  #pragma unroll
  for (int rep = 0; rep < 8; rep++){
    int idx = rep*256 + tid;
    int k = idx >> 4, c4 = idx & 15;
    float4 v = *(const float4*)&W[k*HH + cb + c4*4];
    *(float4*)&Wl[k*64 + c4*4] = v;
  }
  #pragma unroll
  for (int rep = 0; rep < 8; rep++){
    int idx = rep*256 + tid;
    int r = idx >> 5, k4 = idx & 31;
    int row = rb + r;
    float4 v = make_float4(0.f,0.f,0.f,0.f);
    if (row < n) v = *(const float4*)&A[(size_t)row*HH + k4*4];
    int sw = ((r >> 2) & 7) << 2;
    *(float4*)&Hl[r*128 + ((k4*4) ^ sw)] = v;
  }
  __syncthreads();

  int tx = tid & 15, ty = tid >> 4;
  float4 acc0 = make_float4(0,0,0,0), acc1 = acc0, acc2 = acc0, acc3 = acc0;
  int sw = (ty & 7) << 2;
  #pragma unroll 4
  for (int k4 = 0; k4 < 32; k4++){
    int hoff = (k4*4) ^ sw;
    float4 h0 = *(float4*)&Hl[(ty*4+0)*128 + hoff];
    float4 h1 = *(float4*)&Hl[(ty*4+1)*128 + hoff];
    float4 h2 = *(float4*)&Hl[(ty*4+2)*128 + hoff];
    float4 h3 = *(float4*)&Hl[(ty*4+3)*128 + hoff];
    float4 w0 = *(float4*)&Wl[(k4*4+0)*64 + tx*4];
    float4 w1 = *(float4*)&Wl[(k4*4+1)*64 + tx*4];
    float4 w2 = *(float4*)&Wl[(k4*4+2)*64 + tx*4];
    float4 w3 = *(float4*)&Wl[(k4*4+3)*64 + tx*4];
    #define FMA4(ACC,HV) \
      ACC.x = fmaf(HV.x, w0.x, ACC.x); ACC.y = fmaf(HV.x, w0.y, ACC.y); \
      ACC.z = fmaf(HV.x, w0.z, ACC.z); ACC.w = fmaf(HV.x, w0.w, ACC.w); \
      ACC.x = fmaf(HV.y, w1.x, ACC.x); ACC.y = fmaf(HV.y, w1.y, ACC.y); \
      ACC.z = fmaf(HV.y, w1.z, ACC.z); ACC.w = fmaf(HV.y, w1.w, ACC.w); \
      ACC.x = fmaf(HV.z, w2.x, ACC.x); ACC.y = fmaf(HV.z, w2.y, ACC.y); \
      ACC.z = fmaf(HV.z, w2.z, ACC.z); ACC.w = fmaf(HV.z, w2.w, ACC.w); \
      ACC.x = fmaf(HV.w, w3.x, ACC.x); ACC.y = fmaf(HV.w, w3.y, ACC.y); \
      ACC.z = fmaf(HV.w, w3.z, ACC.z); ACC.w = fmaf(HV.w, w3.w, ACC.w);
    FMA4(acc0, h0) FMA4(acc1, h1) FMA4(acc2, h2) FMA4(acc3, h3)
    #undef FMA4
  }

  float mu = 0.f, rsig = 1.f;
  if (mode == 1){ mu = params[0]; rsig = params[1]; }
  int col = cb + tx*4;
  float4 cs4 = make_float4(0,0,0,0), b4 = make_float4(0,0,0,0);
  if (mode == 1) cs4 = *(const float4*)&colsum[col];
  else           b4  = *(const float4*)&bias[col];

  float4 accs[4] = {acc0, acc1, acc2, acc3};
  #pragma unroll
  for (int j = 0; j < 4; j++){
    int row = rb + ty*4 + j;
    if (row < n){
      float4 a = accs[j];
      if (mode == 0){
        a.x = fmaxf(a.x + b4.x, 0.f); a.y = fmaxf(a.y + b4.y, 0.f);
        a.z = fmaxf(a.z + b4.z, 0.f); a.w = fmaxf(a.w + b4.w, 0.f);
        *(float4*)&out[(size_t)row*HH + col] = a;
      } else {
        float d = dinv[row] * rsig;
        a.x = d*(a.x - mu*cs4.x); a.y = d*(a.y - mu*cs4.y);
        a.z = d*(a.z - mu*cs4.z); a.w = d*(a.w - mu*cs4.w);
        uint2 pk;
        pk.x = (unsigned)f2bf(a.x) | ((unsigned)f2bf(a.y) << 16);
        pk.y = (unsigned)f2bf(a.z) | ((unsigned)f2bf(a.w) << 16);
        // row stride = 64 uints = 32 uint2
        ((uint2*)out)[(size_t)row*32 + (cb >> 2) + tx] = pk;
      }
    }
  }
}

// ---------------- Aggregation (pull over CSR, block-per-node, bf16 gathers) --
__global__ __launch_bounds__(128) void aggregate(
    const unsigned short* __restrict__ hw, const int* __restrict__ row_ptr,
    const int* __restrict__ csr, const float* __restrict__ dinv,
    const float* __restrict__ bias, float* __restrict__ hout,
    float2* __restrict__ partials)
{
  int node = blockIdx.x;
  int t = threadIdx.x;
  float acc = bf2f(hw[(size_t)node*HH + t]);   // self loop
  int s0 = row_ptr[node], s1 = row_ptr[node+1];
  int j = s0;
  for (; j + 16 <= s1; j += 16){
    int idx[16];
    #pragma unroll
    for (int u = 0; u < 16; u++) idx[u] = csr[j+u];
    unsigned short v[16];
    #pragma unroll
    for (int u = 0; u < 16; u++) v[u] = hw[(size_t)idx[u]*HH + t];
    #pragma unroll
    for (int u = 0; u < 16; u++) acc += bf2f(v[u]);
  }
  for (; j + 4 <= s1; j += 4){
    int idx[4];
    #pragma unroll
    for (int u = 0; u < 4; u++) idx[u] = csr[j+u];
    unsigned short v[4];
    #pragma unroll
    for (int u = 0; u < 4; u++) v[u] = hw[(size_t)idx[u]*HH + t];
    acc += (bf2f(v[0]) + bf2f(v[1])) + (bf2f(v[2]) + bf2f(v[3]));
  }
  for (; j < s1; j++) acc += bf2f(hw[(size_t)csr[j]*HH + t]);

  float r = fmaxf(acc + bias[t], 0.f);   // dinv folded into gemm output? no:
  // NOTE: dinv[d] applies to the whole sum; gemm only folded dinv of the SOURCE
  // (via pre-scale)?  We keep the round-1/2 formulation: gemm wrote
  // dinv-prescaled rows (hw2 = dinv .* (A@W - mu*cs) * rsig), so the sum needs
  // the destination dinv once more:
  r = fmaxf(fmaf(dinv[node], acc, bias[t]), 0.f);
  hout[(size_t)node*HH + t] = r;

  float s = r, q = r*r;
  for (int off = 32; off > 0; off >>= 1){
    s += __shfl_xor(s, off, 64);
    q += __shfl_xor(q, off, 64);
  }
  __shared__ float sm[4];
  int wave = t >> 6, lane = t & 63;
  if (lane == 0){ sm[wave*2] = s; sm[wave*2+1] = q; }
  __syncthreads();
  if (t == 0) partials[node] = make_float2(sm[0] + sm[2], sm[1] + sm[3]);
}

__global__ __launch_bounds__(1024) void finalize_ln(
    const float2* __restrict__ partials, int n, float* __restrict__ params)
{
  int tid = threadIdx.x;
  float s = 0.f, q = 0.f;
  for (int i = tid; i < n; i += 1024){
    float2 p = partials[i];
    s += p.x; q += p.y;
  }
  for (int off = 32; off > 0; off >>= 1){
    s += __shfl_xor(s, off, 64);
    q += __shfl_xor(q, off, 64);
  }
  __shared__ float ssm[16], qsm[16];
  int wave = tid >> 6, lane = tid & 63;
  if (lane == 0){ ssm[wave] = s; qsm[wave] = q; }
  __syncthreads();
  if (tid == 0){
    float S = 0.f, Q = 0.f;
    for (int w = 0; w < 16; w++){ S += ssm[w]; Q += qsm[w]; }
    const float inv = 1.f / ((float)NN * (float)HH);
    float mu = S * inv;
    float var = Q * inv - mu*mu;
    params[0] = mu;
    params[1] = rsqrtf(var + EPSLN);
  }
}

// ---------------- Pool + MLP + log_softmax ----------------
__global__ __launch_bounds__(128) void pool_mlp(
    const float* __restrict__ h, const int* __restrict__ batch,
    const float* __restrict__ params, const float* __restrict__ W1,
    const float* __restrict__ b1, const float* __restrict__ W2,
    const float* __restrict__ b2, float* __restrict__ out, int n)
{
  __shared__ float pooled[128];
  __shared__ float gact[128];
  __shared__ float sc[16];
  __shared__ int se[2];
  int g = blockIdx.x, tid = threadIdx.x;
  if (tid < 2){
    int v = g + tid;
    int lo = 0, hi = n;
    while (lo < hi){ int mid = (lo+hi) >> 1; if (batch[mid] < v) lo = mid+1; else hi = mid; }
    se[tid] = lo;
  }
  __syncthreads();
  int start = se[0], end = se[1];
  float sum = 0.f;
  for (int v = start; v < end; v++) sum += h[(size_t)v*HH + tid];
  float cnt = (float)((end - start) > 0 ? (end - start) : 1);
  float mu = params[0], rs = params[1];
  pooled[tid] = rs * (sum / cnt - mu);
  __syncthreads();
  float a = b1[tid];
  for (int k = 0; k < HH; k++) a = fmaf(pooled[k], W1[k*HH + tid], a);
  gact[tid] = fmaxf(a, 0.f);
  __syncthreads();
  if (tid < NCLS){
    float s = b2[tid];
    for (int k = 0; k < HH; k++) s = fmaf(gact[k], W2[k*NCLS + tid], s);
    sc[tid] = s;
  }
  __syncthreads();
  if (tid == 0){
    float m = sc[0];
    for (int j = 1; j < NCLS; j++) m = fmaxf(m, sc[j]);
    float lse = 0.f;
    for (int j = 0; j < NCLS; j++) lse += expf(sc[j] - m);
    lse = logf(lse);
    for (int j = 0; j < NCLS; j++) out[g*NCLS + j] = sc[j] - m - lse;
  }
}

// ---------------- launch ----------------
extern "C" void kernel_launch(void* const* d_in, const int* in_sizes, int n_in,
                              void* d_out, int out_size, void* d_ws, size_t ws_size,
                              hipStream_t stream)
{
  const float* x      = (const float*)d_in[0];
  const int*   ei     = (const int*)d_in[1];
  const int*   batch  = (const int*)d_in[2];
  const float* lin1_W = (const float*)d_in[3];
  const float* lin1_b = (const float*)d_in[4];
  const float* conv_W = (const float*)d_in[5];
  const float* conv_b = (const float*)d_in[6];
  const float* mlp_W1 = (const float*)d_in[7];
  const float* mlp_b1 = (const float*)d_in[8];
  const float* mlp_W2 = (const float*)d_in[9];
  const float* mlp_b2 = (const float*)d_in[10];

  const int N = in_sizes[2];      // 100000
  const int E = in_sizes[1] / 2;  // 3200000

  char* ws = (char*)d_ws;
  size_t off = 0;
  auto alloc = [&](size_t bytes)->char*{
    char* p = ws + off; off += (bytes + 255) & ~(size_t)255; return p;
  };
  float*  bufA    = (float*)alloc((size_t)N*HH*4);            // f32 activations
  unsigned short* bufB = (unsigned short*)alloc((size_t)N*HH*2); // bf16 gather table
  int*    csr     = (int*)  alloc((size_t)E*4);
  unsigned long long* ebuf = (unsigned long long*)alloc((size_t)E*8);
  int*    row_ptr = (int*)  alloc((size_t)(N+1)*4);
  float*  dinv    = (float*)alloc((size_t)N*4);
  int*    gbucket = (int*)  alloc((size_t)NB*4);
  int*    bucket_base = (int*)alloc((size_t)(NB+1)*4);
  int*    blkbase = (int*)  alloc((size_t)NBLK*NB*4);
  float*  params  = (float*)alloc(256);
  float*  csums   = (float*)alloc(3*HH*4);
  float2* partials= (float2*)alloc((size_t)N*8);

  const int* srcp = ei;
  const int* dstp = ei + E;

  hipMemsetAsync(gbucket, 0, (size_t)NB*4, stream);
  bucket_hist<<<NBLK, 1024, 0, stream>>>(dstp, E, gbucket, blkbase);
  bucket_scan<<<1, 64, 0, stream>>>(gbucket, bucket_base, E, row_ptr, N, params);
  bucket_scatter<<<NBLK, 1024, 0, stream>>>(srcp, dstp, E, bucket_base, blkbase, ebuf);
  bucket_fill<<<NB, 1024, 0, stream>>>(ebuf, bucket_base, N, row_ptr, dinv, csr);
  colsum_kernel<<<3, 128, 0, stream>>>(conv_W, csums);

  dim3 ggrid((N+63)/64, 2);
  gemm128<<<ggrid, 256, 0, stream>>>(x, lin1_W, lin1_b, nullptr, nullptr, nullptr,
                                     bufA, N, 0);
  for (int i = 0; i < 3; i++){
    gemm128<<<ggrid, 256, 0, stream>>>(bufA, conv_W + (size_t)i*HH*HH, nullptr,
                                       dinv, params + 2*i, csums + i*HH,
                                       (float*)bufB, N, 1);
    aggregate<<<N, 128, 0, stream>>>(bufB, row_ptr, csr, dinv,
                                     conv_b + i*HH, bufA, partials);
    finalize_ln<<<1, 1024, 0, stream>>>(partials, N, params + 2*(i+1));
  }
  pool_mlp<<<NGRAPH, 128, 0, stream>>>(bufA, batch, params + 6,
                                       mlp_W1, mlp_b1, mlp_W2, mlp_b2,
                                       (float*)d_out, N);
}

// Round 4
// 668.422 us; speedup vs baseline: 12.6626x; 1.3226x over previous
//
#include <hip/hip_runtime.h>
#include <math.h>

#define NN 100000
#define HH 128
#define NCLS 10
#define NGRAPH 256
#define EPSLN 1e-5f
#define NB 196          // ceil(100000/512) buckets of 512 nodes
#define NBLK 256        // blocks for hist/scatter passes

typedef __attribute__((ext_vector_type(8))) short short8;
typedef __attribute__((ext_vector_type(4))) float f32x4;

static __device__ __forceinline__ unsigned short f2bf(float f){
  unsigned u = __float_as_uint(f);
  u = u + 0x7fffu + ((u >> 16) & 1u);   // round-to-nearest-even
  return (unsigned short)(u >> 16);
}
static __device__ __forceinline__ float bf2f(unsigned short h){
  return __uint_as_float(((unsigned)h) << 16);
}

// ---------------- Bucketed CSR build ----------------
__global__ __launch_bounds__(1024) void bucket_hist(
    const int* __restrict__ dst, int E,
    int* __restrict__ gbucket, int* __restrict__ blkbase)
{
  __shared__ int lh[NB];
  int tid = threadIdx.x;
  for (int i = tid; i < NB; i += 1024) lh[i] = 0;
  __syncthreads();
  int per = (E + gridDim.x - 1) / gridDim.x;
  int s = blockIdx.x * per, e = min(E, s + per);
  for (int j = s + tid; j < e; j += 1024)
    atomicAdd(&lh[dst[j] >> 9], 1);
  __syncthreads();
  for (int i = tid; i < NB; i += 1024)
    blkbase[blockIdx.x * NB + i] = atomicAdd(&gbucket[i], lh[i]);
}

__global__ void bucket_scan(const int* __restrict__ gbucket,
                            int* __restrict__ bucket_base, int E,
                            int* __restrict__ row_ptr, int N,
                            float* __restrict__ params, float* __restrict__ stats)
{
  if (threadIdx.x == 0 && blockIdx.x == 0){
    int run = 0;
    for (int b = 0; b < NB; b++){ bucket_base[b] = run; run += gbucket[b]; }
    bucket_base[NB] = run;
    row_ptr[N] = E;
    params[0] = 0.f;   // mu for layer-0 conv (no LN yet)
    params[1] = 1.f;   // rsig
    for (int i = 0; i < 6; i++) stats[i] = 0.f;
  }
}

// Pass B: scatter packed (dloc 9b | src 23b) into bucket-ordered ebuf.
__global__ __launch_bounds__(1024) void bucket_scatter(
    const int* __restrict__ src, const int* __restrict__ dst, int E,
    const int* __restrict__ bucket_base, const int* __restrict__ blkbase,
    unsigned* __restrict__ ebuf)
{
  __shared__ int lcur[NB];
  int tid = threadIdx.x;
  for (int i = tid; i < NB; i += 1024)
    lcur[i] = bucket_base[i] + blkbase[blockIdx.x * NB + i];
  __syncthreads();
  int per = (E + gridDim.x - 1) / gridDim.x;
  int s = blockIdx.x * per, e = min(E, s + per);
  for (int j = s + tid; j < e; j += 1024){
    int d = dst[j];
    int p = atomicAdd(&lcur[d >> 9], 1);
    ebuf[p] = (((unsigned)(d & 511)) << 23) | (unsigned)src[j];
  }
}

// Pass C: per bucket: local deg + scan -> row_ptr/dinv, fill csr window.
__global__ __launch_bounds__(1024) void bucket_fill(
    const unsigned* __restrict__ ebuf,
    const int* __restrict__ bucket_base, int N,
    int* __restrict__ row_ptr, float* __restrict__ dinv,
    int* __restrict__ csr)
{
  __shared__ int ldeg[512];
  __shared__ int lscan[512];
  __shared__ int lcur[512];
  int b = blockIdx.x, tid = threadIdx.x;
  int node0 = b << 9;
  int nn = min(512, N - node0);
  for (int i = tid; i < 512; i += 1024) ldeg[i] = 0;
  __syncthreads();
  int s = bucket_base[b], e = bucket_base[b + 1];
  for (int j = s + tid; j < e; j += 1024)
    atomicAdd(&ldeg[ebuf[j] >> 23], 1);
  __syncthreads();
  if (tid < 512) lscan[tid] = ldeg[tid];
  __syncthreads();
  for (int off = 1; off < 512; off <<= 1){
    int v = (tid < 512 && tid >= off) ? lscan[tid - off] : 0;
    __syncthreads();
    if (tid < 512) lscan[tid] += v;
    __syncthreads();
  }
  if (tid < nn){
    int rp = s + lscan[tid] - ldeg[tid];
    row_ptr[node0 + tid] = rp;
    lcur[tid] = rp;
    dinv[node0 + tid] = rsqrtf((float)(ldeg[tid] + 1));  // +1 self-loop
  }
  __syncthreads();
  for (int j = s + tid; j < e; j += 1024){
    unsigned pk = ebuf[j];
    int p = atomicAdd(&lcur[pk >> 23], 1);
    csr[p] = (int)(pk & 0x7fffffu);
  }
}

__global__ void colsum_kernel(const float* __restrict__ W, float* __restrict__ cs){
  const float* w = W + blockIdx.x*HH*HH;
  float s = 0.f;
  for (int k = 0; k < HH; k++) s += w[k*HH + threadIdx.x];
  cs[blockIdx.x*HH + threadIdx.x] = s;
}

// Transpose + bf16-cast the 4 weight matrices: Wt[m][n][k] = bf16(W[m][k][n])
__global__ __launch_bounds__(256) void prep_weights(
    const float* __restrict__ lin1W, const float* __restrict__ convW,
    unsigned short* __restrict__ WtAll)
{
  int m = blockIdx.x;
  const float* srcW = (m == 0) ? lin1W : convW + (size_t)(m-1)*HH*HH;
  unsigned short* dstW = WtAll + (size_t)m*HH*HH;
  for (int i = threadIdx.x; i < HH*HH; i += 256){
    int k = i >> 7, nn2 = i & 127;
    dstW[nn2*HH + k] = f2bf(srcW[i]);
  }
}

// ---------------- MFMA GEMM: out(bf16) = epilogue(A @ W) ----------------
// BM=128, N=128 full, K=128 full. 4 waves x 32 rows. XOR-swizzled LDS.
// mode 0 (lin1, A=f32):  out = relu(A@W + bias)
// mode 1 (conv, A=bf16): out = dinv[row]*rsig*((A@W) - mu*colsum(W))
__global__ __launch_bounds__(256) void gemm_mfma(
    const float* __restrict__ A32, const unsigned short* __restrict__ A16,
    const unsigned short* __restrict__ Wt,
    const float* __restrict__ bias, const float* __restrict__ dinv,
    const float* __restrict__ params, const float* __restrict__ colsum,
    unsigned short* __restrict__ out, int n, int mode)
{
  __shared__ unsigned short As[128*128];  // [row][k] swizzled 16B slots
  __shared__ unsigned short Ws[128*128];  // [n][k]   swizzled 16B slots
  int tid = threadIdx.x;
  int rb = blockIdx.x * 128;

  // stage Wt (bf16, already [n][k])
  #pragma unroll
  for (int rep = 0; rep < 8; rep++){
    int idx = rep*256 + tid;
    int r = idx >> 4, j = idx & 15;
    uint4 v = *(const uint4*)&Wt[r*HH + j*8];
    *(uint4*)&Ws[r*128 + ((j ^ (r & 7)) << 3)] = v;
  }
  // stage A
  if (mode == 1){
    #pragma unroll
    for (int rep = 0; rep < 8; rep++){
      int idx = rep*256 + tid;
      int r = idx >> 4, j = idx & 15;
      int row = rb + r;
      uint4 v = make_uint4(0,0,0,0);
      if (row < n) v = *(const uint4*)&A16[(size_t)row*HH + j*8];
      *(uint4*)&As[r*128 + ((j ^ (r & 7)) << 3)] = v;
    }
  } else {
    #pragma unroll
    for (int rep = 0; rep < 16; rep++){
      int idx = rep*256 + tid;
      int r = idx >> 5, j4 = idx & 31;     // j4: float4 slot (16B in, 8B out)
      int row = rb + r;
      float4 v = make_float4(0,0,0,0);
      if (row < n) v = *(const float4*)&A32[(size_t)row*HH + j4*4];
      uint2 pk;
      pk.x = (unsigned)f2bf(v.x) | ((unsigned)f2bf(v.y) << 16);
      pk.y = (unsigned)f2bf(v.z) | ((unsigned)f2bf(v.w) << 16);
      int uidx = r*128 + ((((j4 >> 1) ^ (r & 7)) << 3)) + (j4 & 1)*4;
      *(uint2*)&As[uidx] = pk;
    }
  }
  __syncthreads();

  int l = tid & 63, w = tid >> 6;
  int lr = l & 15, lk = l >> 4;            // lk in 0..3
  f32x4 acc[2][8];
  #pragma unroll
  for (int mt = 0; mt < 2; mt++)
    #pragma unroll
    for (int nt = 0; nt < 8; nt++) acc[mt][nt] = (f32x4)(0.f);

  #pragma unroll
  for (int kc = 0; kc < 4; kc++){
    short8 af[2];
    #pragma unroll
    for (int mt = 0; mt < 2; mt++){
      int row = w*32 + mt*16 + lr;
      af[mt] = *(const short8*)&As[row*128 + (((kc*4 + lk) ^ (row & 7)) << 3)];
    }
    #pragma unroll
    for (int nt = 0; nt < 8; nt++){
      int col = nt*16 + lr;
      short8 bf = *(const short8*)&Ws[col*128 + (((kc*4 + lk) ^ (col & 7)) << 3)];
      acc[0][nt] = __builtin_amdgcn_mfma_f32_16x16x32_bf16(af[0], bf, acc[0][nt], 0, 0, 0);
      acc[1][nt] = __builtin_amdgcn_mfma_f32_16x16x32_bf16(af[1], bf, acc[1][nt], 0, 0, 0);
    }
  }

  // epilogue: D row = rb + w*32 + mt*16 + lk*4 + r ; col = nt*16 + lr
  float mu = 0.f, rsig = 1.f;
  if (mode == 1){ mu = params[0]; rsig = params[1]; }
  float dvs[2][4];
  #pragma unroll
  for (int mt = 0; mt < 2; mt++)
    #pragma unroll
    for (int r = 0; r < 4; r++){
      int row = rb + w*32 + mt*16 + lk*4 + r;
      dvs[mt][r] = (mode == 1 && row < n) ? dinv[row] : 0.f;
    }
  #pragma unroll
  for (int nt = 0; nt < 8; nt++){
    int col = nt*16 + lr;
    float cs = (mode == 1) ? colsum[col] : 0.f;
    float bb = (mode == 0) ? bias[col] : 0.f;
    #pragma unroll
    for (int mt = 0; mt < 2; mt++){
      #pragma unroll
      for (int r = 0; r < 4; r++){
        int row = rb + w*32 + mt*16 + lk*4 + r;
        if (row < n){
          float a = acc[mt][nt][r];
          float vv = (mode == 0) ? fmaxf(a + bb, 0.f)
                                 : dvs[mt][r] * rsig * (a - mu*cs);
          out[(size_t)row*HH + col] = f2bf(vv);
        }
      }
    }
  }
}

// ---------------- Aggregation (pull over CSR, block-per-node, bf16) --------
__global__ __launch_bounds__(128) void aggregate(
    const unsigned short* __restrict__ hw, const int* __restrict__ row_ptr,
    const int* __restrict__ csr, const float* __restrict__ dinv,
    const float* __restrict__ bias, unsigned short* __restrict__ hout,
    float2* __restrict__ partials)
{
  int node = blockIdx.x;
  int t = threadIdx.x;
  float acc = bf2f(hw[(size_t)node*HH + t]);   // self loop
  int s0 = row_ptr[node], s1 = row_ptr[node+1];
  int j = s0;
  for (; j + 16 <= s1; j += 16){
    int idx[16];
    #pragma unroll
    for (int u = 0; u < 16; u++) idx[u] = __builtin_nontemporal_load(&csr[j+u]);
    unsigned short v[16];
    #pragma unroll
    for (int u = 0; u < 16; u++) v[u] = hw[(size_t)idx[u]*HH + t];
    #pragma unroll
    for (int u = 0; u < 16; u++) acc += bf2f(v[u]);
  }
  for (; j + 4 <= s1; j += 4){
    int idx[4];
    #pragma unroll
    for (int u = 0; u < 4; u++) idx[u] = __builtin_nontemporal_load(&csr[j+u]);
    unsigned short v[4];
    #pragma unroll
    for (int u = 0; u < 4; u++) v[u] = hw[(size_t)idx[u]*HH + t];
    acc += (bf2f(v[0]) + bf2f(v[1])) + (bf2f(v[2]) + bf2f(v[3]));
  }
  for (; j < s1; j++) acc += bf2f(hw[(size_t)csr[j]*HH + t]);

  float r = fmaxf(fmaf(dinv[node], acc, bias[t]), 0.f);
  hout[(size_t)node*HH + t] = f2bf(r);

  float s = r, q = r*r;
  for (int off = 32; off > 0; off >>= 1){
    s += __shfl_xor(s, off, 64);
    q += __shfl_xor(q, off, 64);
  }
  __shared__ float sm[4];
  int wave = t >> 6, lane = t & 63;
  if (lane == 0){ sm[wave*2] = s; sm[wave*2+1] = q; }
  __syncthreads();
  if (t == 0) partials[node] = make_float2(sm[0] + sm[2], sm[1] + sm[3]);
}

__global__ __launch_bounds__(256) void finalize_part(
    const float2* __restrict__ partials, int n, float* __restrict__ stats)
{
  int tid = threadIdx.x;
  float s = 0.f, q = 0.f;
  for (int i = blockIdx.x*256 + tid; i < n; i += gridDim.x*256){
    float2 p = partials[i];
    s += p.x; q += p.y;
  }
  for (int off = 32; off > 0; off >>= 1){
    s += __shfl_xor(s, off, 64);
    q += __shfl_xor(q, off, 64);
  }
  __shared__ float ssm[4], qsm[4];
  int wave = tid >> 6, lane = tid & 63;
  if (lane == 0){ ssm[wave] = s; qsm[wave] = q; }
  __syncthreads();
  if (tid == 0){
    float S = ssm[0]+ssm[1]+ssm[2]+ssm[3];
    float Q = qsm[0]+qsm[1]+qsm[2]+qsm[3];
    atomicAdd(&stats[0], S);
    atomicAdd(&stats[1], Q);
  }
}

__global__ void finalize_fin(const float* __restrict__ stats, float* __restrict__ params){
  if (threadIdx.x == 0){
    const float inv = 1.f / ((float)NN * (float)HH);
    float mu = stats[0] * inv;
    float var = stats[1] * inv - mu*mu;
    params[0] = mu;
    params[1] = rsqrtf(var + EPSLN);
  }
}

// ---------------- Pool + MLP + log_softmax ----------------
__global__ __launch_bounds__(128) void pool_mlp(
    const unsigned short* __restrict__ h, const int* __restrict__ batch,
    const float* __restrict__ params, const float* __restrict__ W1,
    const float* __restrict__ b1, const float* __restrict__ W2,
    const float* __restrict__ b2, float* __restrict__ out, int n)
{
  __shared__ float pooled[128];
  __shared__ float gact[128];
  __shared__ float sc[16];
  __shared__ int se[2];
  int g = blockIdx.x, tid = threadIdx.x;
  if (tid < 2){
    int v = g + tid;
    int lo = 0, hi = n;
    while (lo < hi){ int mid = (lo+hi) >> 1; if (batch[mid] < v) lo = mid+1; else hi = mid; }
    se[tid] = lo;
  }
  __syncthreads();
  int start = se[0], end = se[1];
  float sum = 0.f;
  for (int v = start; v < end; v++) sum += bf2f(h[(size_t)v*HH + tid]);
  float cnt = (float)((end - start) > 0 ? (end - start) : 1);
  float mu = params[0], rs = params[1];
  pooled[tid] = rs * (sum / cnt - mu);
  __syncthreads();
  float a = b1[tid];
  for (int k = 0; k < HH; k++) a = fmaf(pooled[k], W1[k*HH + tid], a);
  gact[tid] = fmaxf(a, 0.f);
  __syncthreads();
  if (tid < NCLS){
    float s = b2[tid];
    for (int k = 0; k < HH; k++) s = fmaf(gact[k], W2[k*NCLS + tid], s);
    sc[tid] = s;
  }
  __syncthreads();
  if (tid == 0){
    float m = sc[0];
    for (int j = 1; j < NCLS; j++) m = fmaxf(m, sc[j]);
    float lse = 0.f;
    for (int j = 0; j < NCLS; j++) lse += expf(sc[j] - m);
    lse = logf(lse);
    for (int j = 0; j < NCLS; j++) out[g*NCLS + j] = sc[j] - m - lse;
  }
}

// ---------------- launch ----------------
extern "C" void kernel_launch(void* const* d_in, const int* in_sizes, int n_in,
                              void* d_out, int out_size, void* d_ws, size_t ws_size,
                              hipStream_t stream)
{
  const float* x      = (const float*)d_in[0];
  const int*   ei     = (const int*)d_in[1];
  const int*   batch  = (const int*)d_in[2];
  const float* lin1_W = (const float*)d_in[3];
  const float* lin1_b = (const float*)d_in[4];
  const float* conv_W = (const float*)d_in[5];
  const float* conv_b = (const float*)d_in[6];
  const float* mlp_W1 = (const float*)d_in[7];
  const float* mlp_b1 = (const float*)d_in[8];
  const float* mlp_W2 = (const float*)d_in[9];
  const float* mlp_b2 = (const float*)d_in[10];

  const int N = in_sizes[2];      // 100000
  const int E = in_sizes[1] / 2;  // 3200000

  char* ws = (char*)d_ws;
  size_t off = 0;
  auto alloc = [&](size_t bytes)->char*{
    char* p = ws + off; off += (bytes + 255) & ~(size_t)255; return p;
  };
  unsigned short* bufA = (unsigned short*)alloc((size_t)N*HH*2); // h (bf16)
  unsigned short* bufB = (unsigned short*)alloc((size_t)N*HH*2); // gather table
  unsigned short* WtAll= (unsigned short*)alloc((size_t)4*HH*HH*2);
  int*      csr     = (int*)     alloc((size_t)E*4);
  unsigned* ebuf    = (unsigned*)alloc((size_t)E*4);
  int*      row_ptr = (int*)     alloc((size_t)(N+1)*4);
  float*    dinv    = (float*)   alloc((size_t)N*4);
  int*      gbucket = (int*)     alloc((size_t)NB*4);
  int*      bucket_base = (int*) alloc((size_t)(NB+1)*4);
  int*      blkbase = (int*)     alloc((size_t)NBLK*NB*4);
  float*    params  = (float*)   alloc(256);
  float*    stats   = (float*)   alloc(256);
  float*    csums   = (float*)   alloc(3*HH*4);
  float2*   partials= (float2*)  alloc((size_t)N*8);

  const int* srcp = ei;
  const int* dstp = ei + E;

  hipMemsetAsync(gbucket, 0, (size_t)NB*4, stream);
  bucket_hist<<<NBLK, 1024, 0, stream>>>(dstp, E, gbucket, blkbase);
  bucket_scan<<<1, 64, 0, stream>>>(gbucket, bucket_base, E, row_ptr, N, params, stats);
  bucket_scatter<<<NBLK, 1024, 0, stream>>>(srcp, dstp, E, bucket_base, blkbase, ebuf);
  bucket_fill<<<NB, 1024, 0, stream>>>(ebuf, bucket_base, N, row_ptr, dinv, csr);
  colsum_kernel<<<3, 128, 0, stream>>>(conv_W, csums);
  prep_weights<<<4, 256, 0, stream>>>(lin1_W, conv_W, WtAll);

  int gblocks = (N + 127) / 128;
  gemm_mfma<<<gblocks, 256, 0, stream>>>(x, nullptr, WtAll, lin1_b,
                                         nullptr, nullptr, nullptr, bufA, N, 0);
  for (int i = 0; i < 3; i++){
    gemm_mfma<<<gblocks, 256, 0, stream>>>(nullptr, bufA, WtAll + (size_t)(i+1)*HH*HH,
                                           nullptr, dinv, params + 2*i, csums + i*HH,
                                           bufB, N, 1);
    aggregate<<<N, 128, 0, stream>>>(bufB, row_ptr, csr, dinv,
                                     conv_b + i*HH, bufA, partials);
    finalize_part<<<128, 256, 0, stream>>>(partials, N, stats + 2*i);
    finalize_fin<<<1, 64, 0, stream>>>(stats + 2*i, params + 2*(i+1));
  }
  pool_mlp<<<NGRAPH, 128, 0, stream>>>(bufA, batch, params + 6,
                                       mlp_W1, mlp_b1, mlp_W2, mlp_b2,
                                       (float*)d_out, N);
}